// Round 4
// baseline (505.296 us; speedup 1.0000x reference)
//
#include <hip/hip_runtime.h>
#include <stdint.h>

#define DD 128

typedef __attribute__((ext_vector_type(8))) short short8;
typedef __attribute__((ext_vector_type(4))) float float4v;

// ---------- bf16 helpers (RTNE) ----------
__device__ __forceinline__ unsigned short f2bf(float f) {
  unsigned u = __float_as_uint(f);
  unsigned r = u + 0x7fffu + ((u >> 16) & 1u);
  return (unsigned short)(r >> 16);
}
__device__ __forceinline__ unsigned pack2(float a, float b) {
  return (unsigned)f2bf(a) | ((unsigned)f2bf(b) << 16);
}
__device__ __forceinline__ float2 unpack2(unsigned p) {
  float2 r;
  r.x = __uint_as_float(p << 16);
  r.y = __uint_as_float(p & 0xffff0000u);
  return r;
}

// ---------- linked-list adjacency build ----------
// next[i] written coalesced; only random traffic is 4B atomicExch into 200KB head (L2-resident).
__global__ __launch_bounds__(256) void k_link(const int* __restrict__ dst, int* head,
                                              int* __restrict__ next, int e) {
  int i = blockIdx.x * 256 + threadIdx.x;
  if (i < e) {
    int old = atomicExch(&head[dst[i]], i);
    next[i] = old;
  }
}

// ---------- weight prep: fp32 [k][n] -> bf16 fragment-major for mfma_16x16x32 B-operand ----------
__global__ __launch_bounds__(256) void k_prep_w(const float* __restrict__ W1, const float* __restrict__ W2,
                                                const float* __restrict__ Wself, const float* __restrict__ Wneigh,
                                                unsigned* __restrict__ wfrag) {
  int gid = blockIdx.x * 256 + threadIdx.x;  // 0 .. 65536
  int m = gid >> 13;
  int r = gid & 8191;
  int p = r & 3;
  int lane = (r >> 2) & 63;
  int t = (r >> 8) & 3;
  int c = r >> 10;
  const float* W;
  if (m == 0) W = W1;
  else if (m == 1) W = W2;
  else if (m < 5) W = Wself + (size_t)(m - 2) * DD * DD;
  else W = Wneigh + (size_t)(m - 5) * DD * DD;
  int n = c * 16 + (lane & 15);
  int k = t * 32 + (lane >> 4) * 8 + 2 * p;
  wfrag[gid] = pack2(W[(size_t)k * DD + n], W[(size_t)(k + 1) * DD + n]);
}

// ---------- mean aggregation via linked-list walk: 2 rows per wave (interleaved chains) ----------
__global__ __launch_bounds__(256) void k_aggr_ll(const unsigned* __restrict__ h, const int* __restrict__ head,
                                                 const int* __restrict__ next, const int* __restrict__ src,
                                                 unsigned* __restrict__ out, int n) {
  int wave = threadIdx.x >> 6, lane = threadIdx.x & 63;
  int w = blockIdx.x * 4 + wave;
  int rA = w * 2, rB = rA + 1;
  if (rA >= n) return;
  int jA = __builtin_amdgcn_readfirstlane(head[rA]);
  int jB = (rB < n) ? __builtin_amdgcn_readfirstlane(head[rB]) : -1;
  float a0 = 0.f, a1 = 0.f, b0 = 0.f, b1 = 0.f;
  int cA = 0, cB = 0;
  while ((jA >= 0) | (jB >= 0)) {
    int sA = 0, nA = -1, sB = 0, nB = -1;
    if (jA >= 0) {
      sA = __builtin_amdgcn_readfirstlane(src[jA]);
      nA = __builtin_amdgcn_readfirstlane(next[jA]);
    }
    if (jB >= 0) {
      sB = __builtin_amdgcn_readfirstlane(src[jB]);
      nB = __builtin_amdgcn_readfirstlane(next[jB]);
    }
    if (jA >= 0) {
      float2 f = unpack2(h[(size_t)sA * 64 + lane]);
      a0 += f.x; a1 += f.y; ++cA;
    }
    if (jB >= 0) {
      float2 f = unpack2(h[(size_t)sB * 64 + lane]);
      b0 += f.x; b1 += f.y; ++cB;
    }
    jA = nA; jB = nB;
  }
  float invA = 1.0f / (float)(cA > 1 ? cA : 1);
  out[(size_t)rA * 64 + lane] = pack2(a0 * invA, a1 * invA);
  if (rB < n) {
    float invB = 1.0f / (float)(cB > 1 ? cB : 1);
    out[(size_t)rB * 64 + lane] = pack2(b0 * invB, b1 * invB);
  }
}

// ---------- MFMA GEMM: out = act(in @ W + b), 64 rows/block, 16 rows/wave ----------
// ACT: 0 none, 1 tanh, 2 silu
template <int ACT, bool INF32, bool OUTF32>
__global__ __launch_bounds__(256) void k_fc(const void* __restrict__ in, const uint4* __restrict__ wfrag,
                                            const float* __restrict__ bias, void* __restrict__ out, int n) {
  __shared__ uint4 sW[2048];  // 32 KB fragment-major weights
  int tid = threadIdx.x;
  for (int i = tid; i < 2048; i += 256) sW[i] = wfrag[i];
  int wave = tid >> 6, lane = tid & 63;
  int quad = lane >> 4, nn = lane & 15;
  int r0 = (blockIdx.x * 4 + wave) * 16;
  int rr = r0 + nn; if (rr >= n) rr = n - 1;
  short8 a[4];
  if (INF32) {
    const float* X = (const float*)in + (size_t)rr * DD;
#pragma unroll
    for (int t = 0; t < 4; ++t) {
      int k0 = t * 32 + quad * 8;
      float4 f0 = *(const float4*)&X[k0];
      float4 f1 = *(const float4*)&X[k0 + 4];
      uint4 u;
      u.x = pack2(f0.x, f0.y); u.y = pack2(f0.z, f0.w);
      u.z = pack2(f1.x, f1.y); u.w = pack2(f1.z, f1.w);
      a[t] = __builtin_bit_cast(short8, u);
    }
  } else {
    const uint4* X = (const uint4*)in + (size_t)rr * (DD / 8);
#pragma unroll
    for (int t = 0; t < 4; ++t) {
      a[t] = __builtin_bit_cast(short8, X[t * 4 + quad]);
    }
  }
  float4v acc[8];
#pragma unroll
  for (int c = 0; c < 8; ++c) acc[c] = (float4v){0.f, 0.f, 0.f, 0.f};
  __syncthreads();
#pragma unroll
  for (int c = 0; c < 8; ++c) {
#pragma unroll
    for (int t = 0; t < 4; ++t) {
      short8 b = __builtin_bit_cast(short8, sW[(c * 4 + t) * 64 + lane]);
      acc[c] = __builtin_amdgcn_mfma_f32_16x16x32_bf16(a[t], b, acc[c], 0, 0, 0);
    }
  }
#pragma unroll
  for (int c = 0; c < 8; ++c) {
    float bcol = bias[c * 16 + nn];
#pragma unroll
    for (int g = 0; g < 4; ++g) {
      int row = r0 + quad * 4 + g;
      if (row < n) {
        float v = acc[c][g] + bcol;
        if (ACT == 1) v = tanhf(v);
        else if (ACT == 2) v = v / (1.f + __expf(-v));
        if (OUTF32) ((float*)out)[(size_t)row * DD + c * 16 + nn] = v;
        else ((unsigned short*)out)[(size_t)row * DD + c * 16 + nn] = f2bf(v);
      }
    }
  }
}

// ---------- MFMA SAGE layer: out = act(X @ Ws + bs + G @ Wn) ----------
template <int ACT, bool OUTF32>
__global__ __launch_bounds__(256) void k_sage(const uint4* __restrict__ X, const uint4* __restrict__ G,
                                              const uint4* __restrict__ wsF, const uint4* __restrict__ wnF,
                                              const float* __restrict__ bias, void* __restrict__ out, int n) {
  __shared__ uint4 sW[4096];  // 64 KB: [0..2047]=Ws frags, [2048..4095]=Wn frags
  int tid = threadIdx.x;
  for (int i = tid; i < 2048; i += 256) {
    sW[i] = wsF[i];
    sW[2048 + i] = wnF[i];
  }
  int wave = tid >> 6, lane = tid & 63;
  int quad = lane >> 4, nn = lane & 15;
  int r0 = (blockIdx.x * 4 + wave) * 16;
  int rr = r0 + nn; if (rr >= n) rr = n - 1;
  short8 a[4], g[4];
  {
    const uint4* Xr = X + (size_t)rr * (DD / 8);
    const uint4* Gr = G + (size_t)rr * (DD / 8);
#pragma unroll
    for (int t = 0; t < 4; ++t) {
      a[t] = __builtin_bit_cast(short8, Xr[t * 4 + quad]);
      g[t] = __builtin_bit_cast(short8, Gr[t * 4 + quad]);
    }
  }
  float4v acc[8];
#pragma unroll
  for (int c = 0; c < 8; ++c) acc[c] = (float4v){0.f, 0.f, 0.f, 0.f};
  __syncthreads();
#pragma unroll
  for (int c = 0; c < 8; ++c) {
#pragma unroll
    for (int t = 0; t < 4; ++t) {
      short8 b = __builtin_bit_cast(short8, sW[(c * 4 + t) * 64 + lane]);
      acc[c] = __builtin_amdgcn_mfma_f32_16x16x32_bf16(a[t], b, acc[c], 0, 0, 0);
    }
#pragma unroll
    for (int t = 0; t < 4; ++t) {
      short8 b = __builtin_bit_cast(short8, sW[2048 + (c * 4 + t) * 64 + lane]);
      acc[c] = __builtin_amdgcn_mfma_f32_16x16x32_bf16(g[t], b, acc[c], 0, 0, 0);
    }
  }
#pragma unroll
  for (int c = 0; c < 8; ++c) {
    float bcol = bias[c * 16 + nn];
#pragma unroll
    for (int gg = 0; gg < 4; ++gg) {
      int row = r0 + quad * 4 + gg;
      if (row < n) {
        float v = acc[c][gg] + bcol;
        if (ACT == 1) v = tanhf(v);
        else if (ACT == 2) v = v / (1.f + __expf(-v));
        if (OUTF32) ((float*)out)[(size_t)row * DD + c * 16 + nn] = v;
        else ((unsigned short*)out)[(size_t)row * DD + c * 16 + nn] = f2bf(v);
      }
    }
  }
}

extern "C" void kernel_launch(void* const* d_in, const int* in_sizes, int n_in,
                              void* d_out, int out_size, void* d_ws, size_t ws_size,
                              hipStream_t stream) {
  const float* h_in = (const float*)d_in[0];
  const int* src    = (const int*)d_in[1];
  const int* dst    = (const int*)d_in[2];
  const float* W1   = (const float*)d_in[3];
  const float* b1   = (const float*)d_in[4];
  const float* W2   = (const float*)d_in[5];
  const float* b2   = (const float*)d_in[6];
  const float* Wself  = (const float*)d_in[7];
  const float* bself  = (const float*)d_in[8];
  const float* Wneigh = (const float*)d_in[9];
  const int N = in_sizes[0] / DD;
  const int E = in_sizes[1];
  float* out = (float*)d_out;

  char* ws = (char*)d_ws;
  size_t off = 0;
  auto alloc = [&](size_t bytes) -> char* {
    char* p = ws + off;
    off = (off + bytes + 255) & ~(size_t)255;
    return p;
  };
  unsigned* wfrag = (unsigned*)alloc(8 * 32768);               // 8 matrices, frag-major bf16
  unsigned* actA  = (unsigned*)alloc((size_t)N * 64 * 4);      // bf16 [N][128]
  unsigned* actB  = (unsigned*)alloc((size_t)N * 64 * 4);
  unsigned* neigh = (unsigned*)alloc((size_t)N * 64 * 4);
  int* head = (int*)alloc((size_t)N * 4);
  int* next = (int*)alloc((size_t)E * 4);

  hipMemsetAsync(head, 0xFF, (size_t)N * 4, stream);  // head[i] = -1
  const int eb = (E + 255) / 256;
  k_link<<<eb, 256, 0, stream>>>(dst, head, next, E);
  k_prep_w<<<256, 256, 0, stream>>>(W1, W2, Wself, Wneigh, wfrag);

  const int gb = (N + 63) / 64;
  const int ab = ((N + 1) / 2 + 3) / 4;  // 2 rows per wave, 4 waves per block
  const uint4* wf = (const uint4*)wfrag;  // 2048 uint4 per matrix

  // fc_in: tanh(h@W1+b1) -> actA ; actA@W2+b2 -> actB
  k_fc<1, true,  false><<<gb, 256, 0, stream>>>(h_in, wf + 0 * 2048, b1, actA, N);
  k_fc<0, false, false><<<gb, 256, 0, stream>>>(actA, wf + 1 * 2048, b2, actB, N);

  const unsigned* cur = actB;
  unsigned* nxt = actA;
  for (int l = 0; l < 3; ++l) {
    k_aggr_ll<<<ab, 256, 0, stream>>>(cur, head, next, src, neigh, N);
    const uint4* wsF = wf + (size_t)(2 + l) * 2048;
    const uint4* wnF = wf + (size_t)(5 + l) * 2048;
    const float* bs = bself + (size_t)l * DD;
    if (l < 2) {
      k_sage<2, false><<<gb, 256, 0, stream>>>((const uint4*)cur, (const uint4*)neigh, wsF, wnF, bs, nxt, N);
      const unsigned* tmp = cur;
      cur = nxt;
      nxt = (unsigned*)tmp;
    } else {
      k_sage<1, true><<<gb, 256, 0, stream>>>((const uint4*)cur, (const uint4*)neigh, wsF, wnF, bs, out, N);
    }
  }
}

// Round 5
// 356.463 us; speedup vs baseline: 1.4175x; 1.4175x over previous
//
#include <hip/hip_runtime.h>
#include <stdint.h>

#define DD 128

typedef __attribute__((ext_vector_type(8))) short short8;
typedef __attribute__((ext_vector_type(4))) float float4v;

// ---------- bf16 helpers (RTNE) ----------
__device__ __forceinline__ unsigned short f2bf(float f) {
  unsigned u = __float_as_uint(f);
  unsigned r = u + 0x7fffu + ((u >> 16) & 1u);
  return (unsigned short)(r >> 16);
}
__device__ __forceinline__ unsigned pack2(float a, float b) {
  return (unsigned)f2bf(a) | ((unsigned)f2bf(b) << 16);
}
__device__ __forceinline__ float2 unpack2(unsigned p) {
  float2 r;
  r.x = __uint_as_float(p << 16);
  r.y = __uint_as_float(p & 0xffff0000u);
  return r;
}

// ---------- CSR build ----------
__global__ __launch_bounds__(256) void k_deg(const int* __restrict__ dst, int* deg, int e) {
  int i = blockIdx.x * 256 + threadIdx.x;
  if (i < e) atomicAdd(&deg[dst[i]], 1);
}

// phase 1: per-block inclusive scan of 1024 elements (coalesced), emit block sums
__global__ __launch_bounds__(1024) void k_scan1(const int* __restrict__ deg, int* __restrict__ incl,
                                                int* __restrict__ bsum, int n) {
  __shared__ int sh[1024];
  int t = threadIdx.x;
  int i = blockIdx.x * 1024 + t;
  int v = (i < n) ? deg[i] : 0;
  sh[t] = v;
  __syncthreads();
#pragma unroll
  for (int off = 1; off < 1024; off <<= 1) {
    int add = (t >= off) ? sh[t - off] : 0;
    __syncthreads();
    sh[t] += add;
    __syncthreads();
  }
  if (i < n) incl[i] = sh[t];
  if (t == 1023) bsum[blockIdx.x] = sh[1023];
}

// phase 2: single-wave exclusive scan of block sums (nb <= 64)
__global__ __launch_bounds__(64) void k_scan2(const int* __restrict__ bsum, int* __restrict__ boff, int nb) {
  int t = threadIdx.x;
  int v = (t < nb) ? bsum[t] : 0;
#pragma unroll
  for (int off = 1; off < 64; off <<= 1) {
    int u = __shfl_up(v, off);
    if ((t & 63) >= off) v += u;
  }
  if (t < nb) boff[t] = v - ((t < nb) ? bsum[t] : 0);  // exclusive
  if (t == 63) boff[nb] = v;
}

// phase 3: emit rowstart/cursor (coalesced)
__global__ __launch_bounds__(1024) void k_scan3(const int* __restrict__ deg, const int* __restrict__ incl,
                                                const int* __restrict__ boff, int* __restrict__ rowstart,
                                                int* __restrict__ cursor, int n) {
  int i = blockIdx.x * 1024 + threadIdx.x;
  if (i >= n) return;
  int d = deg[i];
  int excl = boff[blockIdx.x] + incl[i] - d;
  rowstart[i] = excl;
  cursor[i] = excl;
  if (i == n - 1) rowstart[n] = excl + d;
}

// ---------- range-partitioned fill: range = blockIdx & 7 (XCD round-robin heuristic) ----------
// Each range's esrc write window is ~E/8*4B = 400 KB -> write lines stay L2-resident and
// get fully filled before writeback (kills the 64B-per-4B write-allocate blowup).
__global__ __launch_bounds__(256) void k_fill_r(const int* __restrict__ src, const int* __restrict__ dst,
                                                int* cursor, int* __restrict__ esrc, int e, int rstep) {
  int range = blockIdx.x & 7;
  int i = (blockIdx.x >> 3) * 256 + threadIdx.x;
  if (i >= e) return;
  int d = dst[i];
  int lo = range * rstep;
  if (d >= lo && d < lo + rstep) {
    int p = atomicAdd(&cursor[d], 1);
    esrc[p] = src[i];
  }
}

// ---------- weight prep: fp32 [k][n] -> bf16 fragment-major for mfma_16x16x32 B-operand ----------
__global__ __launch_bounds__(256) void k_prep_w(const float* __restrict__ W1, const float* __restrict__ W2,
                                                const float* __restrict__ Wself, const float* __restrict__ Wneigh,
                                                unsigned* __restrict__ wfrag) {
  int gid = blockIdx.x * 256 + threadIdx.x;  // 0 .. 65536
  int m = gid >> 13;
  int r = gid & 8191;
  int p = r & 3;
  int lane = (r >> 2) & 63;
  int t = (r >> 8) & 3;
  int c = r >> 10;
  const float* W;
  if (m == 0) W = W1;
  else if (m == 1) W = W2;
  else if (m < 5) W = Wself + (size_t)(m - 2) * DD * DD;
  else W = Wneigh + (size_t)(m - 5) * DD * DD;
  int n = c * 16 + (lane & 15);
  int k = t * 32 + (lane >> 4) * 8 + 2 * p;
  wfrag[gid] = pack2(W[(size_t)k * DD + n], W[(size_t)(k + 1) * DD + n]);
}

// ---------- mean aggregation: one wave per row, 4 groups x 16 lanes, dwordx4 gathers ----------
__global__ __launch_bounds__(256) void k_aggr4(const uint4* __restrict__ h, const int* __restrict__ rowstart,
                                               const int* __restrict__ esrc,
                                               uint4* __restrict__ out, int n) {
  int wave = threadIdx.x >> 6, lane = threadIdx.x & 63;
  int g = lane >> 4, nn = lane & 15;
  int r = blockIdx.x * 4 + wave;
  if (r >= n) return;
  int ru = __builtin_amdgcn_readfirstlane(r);
  int beg = rowstart[ru], end = rowstart[ru + 1];
  int cnt = end - beg;
  float acc[8];
#pragma unroll
  for (int i = 0; i < 8; ++i) acc[i] = 0.f;
  int base = 0;
  for (; base + 8 <= cnt; base += 8) {
    int j0 = beg + base + g;
    int s0 = esrc[j0];
    int s1 = esrc[j0 + 4];
    uint4 v0 = h[(size_t)s0 * 16 + nn];
    uint4 v1 = h[(size_t)s1 * 16 + nn];
    const unsigned* w0 = (const unsigned*)&v0;
    const unsigned* w1 = (const unsigned*)&v1;
#pragma unroll
    for (int k = 0; k < 4; ++k) {
      float2 f0 = unpack2(w0[k]);
      float2 f1 = unpack2(w1[k]);
      acc[2 * k] += f0.x + f1.x;
      acc[2 * k + 1] += f0.y + f1.y;
    }
  }
  for (; base < cnt; base += 4) {
    if (base + g < cnt) {
      int s = esrc[beg + base + g];
      uint4 v = h[(size_t)s * 16 + nn];
      const unsigned* w = (const unsigned*)&v;
#pragma unroll
      for (int k = 0; k < 4; ++k) {
        float2 f = unpack2(w[k]);
        acc[2 * k] += f.x;
        acc[2 * k + 1] += f.y;
      }
    }
  }
#pragma unroll
  for (int k = 0; k < 8; ++k) {
    acc[k] += __shfl_xor(acc[k], 16, 64);
    acc[k] += __shfl_xor(acc[k], 32, 64);
  }
  if (g == 0) {
    float inv = 1.0f / (float)(cnt > 1 ? cnt : 1);
    uint4 o;
    o.x = pack2(acc[0] * inv, acc[1] * inv);
    o.y = pack2(acc[2] * inv, acc[3] * inv);
    o.z = pack2(acc[4] * inv, acc[5] * inv);
    o.w = pack2(acc[6] * inv, acc[7] * inv);
    out[(size_t)r * 16 + nn] = o;
  }
}

// ---------- MFMA GEMM: out = act(in @ W + b), 64 rows/block, 16 rows/wave ----------
// ACT: 0 none, 1 tanh, 2 silu
template <int ACT, bool INF32, bool OUTF32>
__global__ __launch_bounds__(256) void k_fc(const void* __restrict__ in, const uint4* __restrict__ wfrag,
                                            const float* __restrict__ bias, void* __restrict__ out, int n) {
  __shared__ uint4 sW[2048];  // 32 KB fragment-major weights
  int tid = threadIdx.x;
  for (int i = tid; i < 2048; i += 256) sW[i] = wfrag[i];
  int wave = tid >> 6, lane = tid & 63;
  int quad = lane >> 4, nn = lane & 15;
  int r0 = (blockIdx.x * 4 + wave) * 16;
  int rr = r0 + nn; if (rr >= n) rr = n - 1;
  short8 a[4];
  if (INF32) {
    const float* X = (const float*)in + (size_t)rr * DD;
#pragma unroll
    for (int t = 0; t < 4; ++t) {
      int k0 = t * 32 + quad * 8;
      float4 f0 = *(const float4*)&X[k0];
      float4 f1 = *(const float4*)&X[k0 + 4];
      uint4 u;
      u.x = pack2(f0.x, f0.y); u.y = pack2(f0.z, f0.w);
      u.z = pack2(f1.x, f1.y); u.w = pack2(f1.z, f1.w);
      a[t] = __builtin_bit_cast(short8, u);
    }
  } else {
    const uint4* X = (const uint4*)in + (size_t)rr * (DD / 8);
#pragma unroll
    for (int t = 0; t < 4; ++t) {
      a[t] = __builtin_bit_cast(short8, X[t * 4 + quad]);
    }
  }
  float4v acc[8];
#pragma unroll
  for (int c = 0; c < 8; ++c) acc[c] = (float4v){0.f, 0.f, 0.f, 0.f};
  __syncthreads();
#pragma unroll
  for (int c = 0; c < 8; ++c) {
#pragma unroll
    for (int t = 0; t < 4; ++t) {
      short8 b = __builtin_bit_cast(short8, sW[(c * 4 + t) * 64 + lane]);
      acc[c] = __builtin_amdgcn_mfma_f32_16x16x32_bf16(a[t], b, acc[c], 0, 0, 0);
    }
  }
#pragma unroll
  for (int c = 0; c < 8; ++c) {
    float bcol = bias[c * 16 + nn];
#pragma unroll
    for (int g = 0; g < 4; ++g) {
      int row = r0 + quad * 4 + g;
      if (row < n) {
        float v = acc[c][g] + bcol;
        if (ACT == 1) v = tanhf(v);
        else if (ACT == 2) v = v / (1.f + __expf(-v));
        if (OUTF32) ((float*)out)[(size_t)row * DD + c * 16 + nn] = v;
        else ((unsigned short*)out)[(size_t)row * DD + c * 16 + nn] = f2bf(v);
      }
    }
  }
}

// ---------- MFMA SAGE layer: out = act(X @ Ws + bs + G @ Wn) ----------
template <int ACT, bool OUTF32>
__global__ __launch_bounds__(256) void k_sage(const uint4* __restrict__ X, const uint4* __restrict__ G,
                                              const uint4* __restrict__ wsF, const uint4* __restrict__ wnF,
                                              const float* __restrict__ bias, void* __restrict__ out, int n) {
  __shared__ uint4 sW[4096];  // 64 KB: [0..2047]=Ws frags, [2048..4095]=Wn frags
  int tid = threadIdx.x;
  for (int i = tid; i < 2048; i += 256) {
    sW[i] = wsF[i];
    sW[2048 + i] = wnF[i];
  }
  int wave = tid >> 6, lane = tid & 63;
  int quad = lane >> 4, nn = lane & 15;
  int r0 = (blockIdx.x * 4 + wave) * 16;
  int rr = r0 + nn; if (rr >= n) rr = n - 1;
  short8 a[4], g[4];
  {
    const uint4* Xr = X + (size_t)rr * (DD / 8);
    const uint4* Gr = G + (size_t)rr * (DD / 8);
#pragma unroll
    for (int t = 0; t < 4; ++t) {
      a[t] = __builtin_bit_cast(short8, Xr[t * 4 + quad]);
      g[t] = __builtin_bit_cast(short8, Gr[t * 4 + quad]);
    }
  }
  float4v acc[8];
#pragma unroll
  for (int c = 0; c < 8; ++c) acc[c] = (float4v){0.f, 0.f, 0.f, 0.f};
  __syncthreads();
#pragma unroll
  for (int c = 0; c < 8; ++c) {
#pragma unroll
    for (int t = 0; t < 4; ++t) {
      short8 b = __builtin_bit_cast(short8, sW[(c * 4 + t) * 64 + lane]);
      acc[c] = __builtin_amdgcn_mfma_f32_16x16x32_bf16(a[t], b, acc[c], 0, 0, 0);
    }
#pragma unroll
    for (int t = 0; t < 4; ++t) {
      short8 b = __builtin_bit_cast(short8, sW[2048 + (c * 4 + t) * 64 + lane]);
      acc[c] = __builtin_amdgcn_mfma_f32_16x16x32_bf16(g[t], b, acc[c], 0, 0, 0);
    }
  }
#pragma unroll
  for (int c = 0; c < 8; ++c) {
    float bcol = bias[c * 16 + nn];
#pragma unroll
    for (int gg = 0; gg < 4; ++gg) {
      int row = r0 + quad * 4 + gg;
      if (row < n) {
        float v = acc[c][gg] + bcol;
        if (ACT == 1) v = tanhf(v);
        else if (ACT == 2) v = v / (1.f + __expf(-v));
        if (OUTF32) ((float*)out)[(size_t)row * DD + c * 16 + nn] = v;
        else ((unsigned short*)out)[(size_t)row * DD + c * 16 + nn] = f2bf(v);
      }
    }
  }
}

extern "C" void kernel_launch(void* const* d_in, const int* in_sizes, int n_in,
                              void* d_out, int out_size, void* d_ws, size_t ws_size,
                              hipStream_t stream) {
  const float* h_in = (const float*)d_in[0];
  const int* src    = (const int*)d_in[1];
  const int* dst    = (const int*)d_in[2];
  const float* W1   = (const float*)d_in[3];
  const float* b1   = (const float*)d_in[4];
  const float* W2   = (const float*)d_in[5];
  const float* b2   = (const float*)d_in[6];
  const float* Wself  = (const float*)d_in[7];
  const float* bself  = (const float*)d_in[8];
  const float* Wneigh = (const float*)d_in[9];
  const int N = in_sizes[0] / DD;
  const int E = in_sizes[1];
  float* out = (float*)d_out;

  char* ws = (char*)d_ws;
  size_t off = 0;
  auto alloc = [&](size_t bytes) -> char* {
    char* p = ws + off;
    off = (off + bytes + 255) & ~(size_t)255;
    return p;
  };
  unsigned* wfrag = (unsigned*)alloc(8 * 32768);               // 8 matrices, frag-major bf16
  unsigned* actA  = (unsigned*)alloc((size_t)N * 64 * 4);      // bf16 [N][128]
  unsigned* actB  = (unsigned*)alloc((size_t)N * 64 * 4);
  unsigned* neigh = (unsigned*)alloc((size_t)N * 64 * 4);
  int* esrc     = (int*)alloc((size_t)E * 4);
  int* degi     = (int*)alloc((size_t)N * 4);
  int* rowstart = (int*)alloc((size_t)(N + 1) * 4);
  int* cursor   = (int*)alloc((size_t)N * 4);
  int* incl     = (int*)alloc((size_t)N * 4);
  int* bsum     = (int*)alloc(65 * 4);
  int* boff     = (int*)alloc(65 * 4);

  hipMemsetAsync(degi, 0, (size_t)N * 4, stream);
  const int eb = (E + 255) / 256;
  const int nb = (N + 1023) / 1024;  // 49 <= 64
  const int rstep = (N + 7) / 8;
  k_deg<<<eb, 256, 0, stream>>>(dst, degi, E);
  k_scan1<<<nb, 1024, 0, stream>>>(degi, incl, bsum, N);
  k_scan2<<<1, 64, 0, stream>>>(bsum, boff, nb);
  k_scan3<<<nb, 1024, 0, stream>>>(degi, incl, boff, rowstart, cursor, N);
  k_fill_r<<<eb * 8, 256, 0, stream>>>(src, dst, cursor, esrc, E, rstep);
  k_prep_w<<<256, 256, 0, stream>>>(W1, W2, Wself, Wneigh, wfrag);

  const int gb = (N + 63) / 64;
  const int ab = (N + 3) / 4;
  const uint4* wf = (const uint4*)wfrag;  // 2048 uint4 per matrix

  // fc_in: tanh(h@W1+b1) -> actA ; actA@W2+b2 -> actB
  k_fc<1, true,  false><<<gb, 256, 0, stream>>>(h_in, wf + 0 * 2048, b1, actA, N);
  k_fc<0, false, false><<<gb, 256, 0, stream>>>(actA, wf + 1 * 2048, b2, actB, N);

  const unsigned* cur = actB;
  unsigned* nxt = actA;
  for (int l = 0; l < 3; ++l) {
    k_aggr4<<<ab, 256, 0, stream>>>((const uint4*)cur, rowstart, esrc, (uint4*)neigh, N);
    const uint4* wsF = wf + (size_t)(2 + l) * 2048;
    const uint4* wnF = wf + (size_t)(5 + l) * 2048;
    const float* bs = bself + (size_t)l * DD;
    if (l < 2) {
      k_sage<2, false><<<gb, 256, 0, stream>>>((const uint4*)cur, (const uint4*)neigh, wsF, wnF, bs, nxt, N);
      const unsigned* tmp = cur;
      cur = nxt;
      nxt = (unsigned*)tmp;
    } else {
      k_sage<1, true><<<gb, 256, 0, stream>>>((const uint4*)cur, (const uint4*)neigh, wsF, wnF, bs, out, N);
    }
  }
}